// Round 6
// baseline (104.681 us; speedup 1.0000x reference)
//
#include <hip/hip_runtime.h>
#include <hip/hip_bf16.h>
#include <stdint.h>

typedef unsigned short u16;
typedef short short8 __attribute__((ext_vector_type(8)));
typedef float f32x4 __attribute__((ext_vector_type(4)));

#define SEQ 2048
#define EMB 1024
#define NH 16
#define HD 64
#define ZP 2112  // SEQ + 64 pad, reversed z per (b,h)

__device__ inline u16 f2bf(float f) {
    uint32_t u = __builtin_bit_cast(uint32_t, f);
    uint32_t r = (u + 0x7FFFu + ((u >> 16) & 1u)) >> 16;
    return (u16)r;
}

__device__ inline void gload16(const void* g, void* l) {
    __builtin_amdgcn_global_load_lds(
        (const __attribute__((address_space(1))) void*)g,
        (__attribute__((address_space(3))) void*)l, 16, 0, 0);
}

// ---------------- all casts fused: x, W_V, W_O fp32 -> bf16 ----------------
__global__ __launch_bounds__(256) void cast_all(const float* __restrict__ x,
                                                const float* __restrict__ W_V,
                                                const float* __restrict__ W_O,
                                                u16* __restrict__ xb,
                                                u16* __restrict__ wvb,
                                                u16* __restrict__ wob) {
    int bid = blockIdx.x, t = threadIdx.x;
    const float* src;
    u16* dst;
    int j;
    if (bid < 4096) { j = bid * 256 + t; src = x; dst = xb; }
    else {
        j = (bid - 4096) * 256 + t;
        if (j < 262144) { src = W_V; dst = wvb; }
        else { j -= 262144; src = W_O; dst = wob; }
    }
    float4 f = reinterpret_cast<const float4*>(src)[j];
    union { u16 u[4]; uint2 v; } o;
    o.u[0] = f2bf(f.x); o.u[1] = f2bf(f.y); o.u[2] = f2bf(f.z); o.u[3] = f2bf(f.w);
    reinterpret_cast<uint2*>(dst)[j] = o.v;
}

// ---------------- logits: zl[b][h][s] = dot(x[b,s,:], W_A[h,:]) * 0.125 ----------------
__global__ __launch_bounds__(256) void logits_kernel(const float* __restrict__ x,
                                                     const float* __restrict__ W_A,
                                                     float* __restrict__ zl) {
    __shared__ float wa[NH * EMB]; // 64 KB
    int t = threadIdx.x;
    for (int i = t; i < NH * EMB / 4; i += 256)
        reinterpret_cast<float4*>(wa)[i] = reinterpret_cast<const float4*>(W_A)[i];
    __syncthreads();
    int w = t >> 6, l = t & 63;
    int row0 = blockIdx.x * 16 + w * 4;
    for (int rr = 0; rr < 4; rr++) {
        int gs = row0 + rr;           // 0..4095 = b*SEQ + s
        int b = gs >> 11, s = gs & 2047;
        const float* xr = x + (size_t)gs * EMB;
        float xv[16];
#pragma unroll
        for (int q = 0; q < 16; q++) xv[q] = xr[l + 64 * q];
#pragma unroll
        for (int h = 0; h < NH; h++) {
            float a = 0.f;
#pragma unroll
            for (int q = 0; q < 16; q++) a += xv[q] * wa[h * EMB + l + 64 * q];
#pragma unroll
            for (int off = 32; off; off >>= 1) a += __shfl_xor(a, off);
            if (l == h) zl[((size_t)b * NH + h) * SEQ + s] = a * 0.125f;
        }
    }
}

// ---------------- softmax body (per bh), 512 threads ----------------
__device__ void softmax_body512(const float* __restrict__ zl, u16* __restrict__ zr, int bh) {
    const float* src = zl + (size_t)bh * SEQ;
    int t = threadIdx.x;
    int w = t >> 6, l = t & 63;
    __shared__ float red[8];
    __shared__ float bc;
    float v[4];
#pragma unroll
    for (int q = 0; q < 4; q++) v[q] = src[t + 512 * q];
    float m = fmaxf(fmaxf(v[0], v[1]), fmaxf(v[2], v[3]));
#pragma unroll
    for (int off = 32; off; off >>= 1) m = fmaxf(m, __shfl_xor(m, off));
    if (l == 0) red[w] = m;
    __syncthreads();
    if (t == 0) {
        float mm = red[0];
#pragma unroll
        for (int q = 1; q < 8; q++) mm = fmaxf(mm, red[q]);
        bc = mm;
    }
    __syncthreads();
    m = bc;
    float s = 0.f;
#pragma unroll
    for (int q = 0; q < 4; q++) { v[q] = expf(v[q] - m); s += v[q]; }
#pragma unroll
    for (int off = 32; off; off >>= 1) s += __shfl_xor(s, off);
    if (l == 0) red[w] = s;
    __syncthreads();
    if (t == 0) {
        float ss = 0.f;
#pragma unroll
        for (int q = 0; q < 8; q++) ss += red[q];
        bc = ss;
    }
    __syncthreads();
    float inv = 1.0f / bc;
#pragma unroll
    for (int q = 0; q < 4; q++) {
        int sidx = t + 512 * q;
        zr[(size_t)bh * ZP + (SEQ - 1 - sidx)] = f2bf(v[q] * inv);
    }
    if (t < ZP - SEQ) zr[(size_t)bh * ZP + SEQ + t] = 0;
}

// ---------------- GEMM: C[M,N] = A[M,K] * B[N,K]^T ----------------
// 128x128 tile, 512 threads (8 waves 2x4, wave tile 64x32), BK=64, dbuf.
// T3+T4: counted vmcnt(4) + raw s_barrier -- NEVER vmcnt(0) in the main loop.
// Loop invariant: iter kt stages tile kt+1 into buf[(kt+1)&1] (4 gload16/thread),
// waits vmcnt(4) (=> tile kt staged by prev iter is complete), barrier, computes
// buf[kt&1], barrier (WAR: tile kt+2 overwrites buf[kt&1] only after all reads).
// Linear LDS dest + pre-swizzled global src + XOR'd ds_read (rule #21).
// XCD-chunked bijective swizzle: 256 blocks -> 32 consecutive wg per XCD.
// OUTMODE 0: bf16 out; 1: fp32 out + bias.  SM: blocks >=256 run softmax.
template <int OUTMODE, int MAP, bool SM>
__global__ __launch_bounds__(512) void gemm128(const u16* __restrict__ A,
                                               const u16* __restrict__ Bw,
                                               u16* __restrict__ Cb, float* __restrict__ Cf,
                                               const float* __restrict__ bias,
                                               int M, int N, int K,
                                               const float* __restrict__ zl,
                                               u16* __restrict__ zr) {
    if constexpr (SM) {
        if (blockIdx.x >= 256) { softmax_body512(zl, zr, blockIdx.x - 256); return; }
    }
    __shared__ u16 As[2][128 * 64];
    __shared__ u16 Bs[2][128 * 64];
    const int t = threadIdx.x;
    const int i = blockIdx.x;
    const int wg = (i & 7) * 32 + (i >> 3);   // XCD-chunked, bijective for 256
    int xg, yg;
    if constexpr (MAP == 0) { xg = wg >> 3; yg = wg & 7; }   // share A across xg
    else                    { yg = wg >> 3; xg = wg & 7; }
    const int m0 = yg * 128, n0 = xg * 128;
    const int w = t >> 6, l = t & 63;
    const int wr = w >> 2, wc = w & 3;        // wave tile 64 rows x 32 cols
    const int lrow = l & 15, lk = l >> 4;
    const int r7 = lrow & 7;

    // staging: wave w stages rows w*16..w*16+15 of A and B (2 gload16 each)
    const int srow = w * 16 + (l >> 3);
    const int scb = ((l & 7) ^ (l >> 3)) * 8;   // pre-swizzled source col (bf16)
    const u16* gA0 = A + (size_t)(m0 + srow) * K + scb;
    const u16* gA1 = gA0 + (size_t)8 * K;
    const u16* gB0 = Bw + (size_t)(n0 + srow) * K + scb;
    const u16* gB1 = gB0 + (size_t)8 * K;
    const int ldsbase = w * 16 * 64;            // u16 units

    f32x4 acc[4][2];
#pragma unroll
    for (int a = 0; a < 4; a++)
#pragma unroll
        for (int b = 0; b < 2; b++) acc[a][b] = (f32x4){0.f, 0.f, 0.f, 0.f};

    const int NT = K >> 6;
    // prologue: stage tile 0 into buf 0 (4 loads in flight)
    gload16(gA0, &As[0][ldsbase]);
    gload16(gA1, &As[0][ldsbase + 512]);
    gload16(gB0, &Bs[0][ldsbase]);
    gload16(gB1, &Bs[0][ldsbase + 512]);

    for (int kt = 0; kt < NT; kt++) {
        const int cur = kt & 1;
        if (kt + 1 < NT) {
            const int k0 = (kt + 1) * 64;
            gload16(gA0 + k0, &As[cur ^ 1][ldsbase]);
            gload16(gA1 + k0, &As[cur ^ 1][ldsbase + 512]);
            gload16(gB0 + k0, &Bs[cur ^ 1][ldsbase]);
            gload16(gB1 + k0, &Bs[cur ^ 1][ldsbase + 512]);
            asm volatile("s_waitcnt vmcnt(4)" ::: "memory");  // tile kt landed; kt+1 in flight
        } else {
            asm volatile("s_waitcnt vmcnt(0)" ::: "memory");
        }
        __builtin_amdgcn_sched_barrier(0);
        __builtin_amdgcn_s_barrier();            // all waves' tile kt in LDS
#pragma unroll
        for (int kk = 0; kk < 2; kk++) {
            const int cs = ((kk * 4 + lk) ^ r7) * 8;
            short8 af[4], bf2[2];
#pragma unroll
            for (int mi = 0; mi < 4; mi++)
                af[mi] = *reinterpret_cast<const short8*>(
                    &As[cur][(wr * 64 + mi * 16 + lrow) * 64 + cs]);
#pragma unroll
            for (int ni = 0; ni < 2; ni++)
                bf2[ni] = *reinterpret_cast<const short8*>(
                    &Bs[cur][(wc * 32 + ni * 16 + lrow) * 64 + cs]);
#pragma unroll
            for (int mi = 0; mi < 4; mi++)
#pragma unroll
                for (int ni = 0; ni < 2; ni++)
                    acc[mi][ni] = __builtin_amdgcn_mfma_f32_16x16x32_bf16(af[mi], bf2[ni], acc[mi][ni], 0, 0, 0);
        }
        __builtin_amdgcn_s_barrier();            // WAR: reads done before overwrite
    }
#pragma unroll
    for (int mi = 0; mi < 4; mi++)
#pragma unroll
        for (int ni = 0; ni < 2; ni++)
#pragma unroll
            for (int r = 0; r < 4; r++) {
                int row = m0 + wr * 64 + mi * 16 + lk * 4 + r;
                int col = n0 + wc * 32 + ni * 16 + lrow;
                if constexpr (OUTMODE == 0)
                    Cb[(size_t)row * N + col] = f2bf(acc[mi][ni][r]);
                else
                    Cf[(size_t)row * N + col] = acc[mi][ni][r] + bias[col];
            }
}

// ---------------- causal Toeplitz conv, barrier-free ----------------
// out[b,i,h,:] = sum_{j<=i} z[b,h,i-j] * v[b,j,h,:]
// A[row][k] = zrev[2047-row+k]: fragments read directly from dual-parity LDS
// copies of zrev; B fragments from v^T in global (L2-resident via XCD swizzle).
// 2048 wave-tasks: (bh, slice-pair (s,63-s) of 32 rows, col-half); 65 K32-steps
// each (uniform). 512 blocks -> 2 waves/SIMD. Depth-2 B prefetch (static names).
__global__ __launch_bounds__(256) void conv_kernel(const u16* __restrict__ zr,
                                                   const u16* __restrict__ vt2,
                                                   u16* __restrict__ cv) {
    const int i = blockIdx.x;
    const int bh = (i & 7) * 4 + ((i >> 3) & 3);
    const int rest = i >> 5;                   // 0..15
    const int b = bh >> 4, h = bh & 15;
    __shared__ uint zsl[2176];  // [0..1087]=zrev dwords, [1088..]=shift-by-1-elem
    const int t = threadIdx.x;
    {
        const uint* zp = reinterpret_cast<const uint*>(zr + (size_t)bh * ZP);
        for (int q = t; q < 1088; q += 256) {
            uint v0 = (q < 1056) ? zp[q] : 0u;
            uint v1 = (q < 1055) ? zp[q + 1] : 0u;
            zsl[q] = v0;
            zsl[1088 + q] = (v0 >> 16) | (v1 << 16);
        }
    }
    __syncthreads();

    const int w = t >> 6, l = t & 63;
    const int task = rest * 4 + w;             // 0..63
    const int pp = task >> 1;                  // 0..31
    const int ch = task & 1;
    const int lrow = l & 15;
    const int lk8 = (l >> 4) * 8;
    const int col0 = ch * 32;
    const int ebase = h * 64 + col0;
    const size_t boff = (size_t)b * SEQ;

    union U { uint d[4]; short8 s8; };

    int slices[2] = {pp, 63 - pp};
#pragma unroll 1
    for (int si = 0; si < 2; si++) {
        const int s = slices[si];
        const int row0 = s * 32;
        const int nk = s + 1;                  // K32 steps
        f32x4 acc[2][2];
#pragma unroll
        for (int a = 0; a < 2; a++)
#pragma unroll
            for (int c = 0; c < 2; c++) acc[a][c] = (f32x4){0.f, 0.f, 0.f, 0.f};

        const int obase = 2047 - row0 - lrow + lk8;

        auto loadB = [&](int k0, U* bf) {
#pragma unroll
            for (int ni = 0; ni < 2; ni++) {
                const u16* p = vt2 + (((size_t)(ebase + ni * 16 + lrow)) << 12) + boff + k0 + lk8;
                *reinterpret_cast<uint4*>(bf[ni].d) = *reinterpret_cast<const uint4*>(p);
            }
        };
        auto loadA = [&](int k0, U* af) {
#pragma unroll
            for (int mi = 0; mi < 2; mi++) {
                int o = obase - mi * 16 + k0;
                uint adw = (uint)(o >> 1) + (uint)((o & 1) * 1088);
#pragma unroll
                for (int q = 0; q < 4; q++) af[mi].d[q] = zsl[adw + q];
            }
        };

        U a0[2], a1[2], b0[2], b1[2];
        loadB(0, b0);
        loadB(32, b1);          // harmless over-read if nk==1 (in-bounds)
        loadA(0, a0);
        int k = 0;
        for (; k + 1 < nk; k += 2) {
            loadA((k + 1) * 32, a1);
#pragma unroll
            for (int mi = 0; mi < 2; mi++)
#pragma unroll
                for (int ni = 0; ni < 2; ni++)
                    acc[mi][ni] = __builtin_amdgcn_mfma_f32_16x16x32_bf16(a0[mi].s8, b0[ni].s8, acc[mi][ni], 0, 0, 0);
            if (k + 2 < nk) loadB((k + 2) * 32, b0);
            loadA((k + 2) * 32, a0);   // over-read stays inside zsl (pad analyzed)
#pragma unroll
            for (int mi = 0; mi < 2; mi++)
#pragma unroll
                for (int ni = 0; ni < 2; ni++)
                    acc[mi][ni] = __builtin_amdgcn_mfma_f32_16x16x32_bf16(a1[mi].s8, b1[ni].s8, acc[mi][ni], 0, 0, 0);
            if (k + 3 < nk) loadB((k + 3) * 32, b1);
        }
        if (nk & 1) {
#pragma unroll
            for (int mi = 0; mi < 2; mi++)
#pragma unroll
                for (int ni = 0; ni < 2; ni++)
                    acc[mi][ni] = __builtin_amdgcn_mfma_f32_16x16x32_bf16(a0[mi].s8, b0[ni].s8, acc[mi][ni], 0, 0, 0);
        }
#pragma unroll
        for (int mi = 0; mi < 2; mi++)
#pragma unroll
            for (int ni = 0; ni < 2; ni++)
#pragma unroll
                for (int r = 0; r < 4; r++) {
                    int row = row0 + mi * 16 + (l >> 4) * 4 + r;
                    int col = col0 + ni * 16 + lrow;
                    cv[((size_t)b * SEQ + row) * EMB + h * 64 + col] = f2bf(acc[mi][ni][r]);
                }
    }
}

extern "C" void kernel_launch(void* const* d_in, const int* in_sizes, int n_in,
                              void* d_out, int out_size, void* d_ws, size_t ws_size,
                              hipStream_t stream) {
    const float* x   = (const float*)d_in[0];
    const float* W_A = (const float*)d_in[1];
    const float* W_V = (const float*)d_in[2];
    const float* W_O = (const float*)d_in[3];
    const float* b_O = (const float*)d_in[4];

    char* ws = (char*)d_ws;
    u16*   xb  = (u16*)(ws + 0);          // 8 MB   x bf16 [4096][1024]
    u16*   wvb = (u16*)(ws + 8388608);    // 2 MB   W_V bf16 [1024][1024]
    u16*   wob = (u16*)(ws + 10485760);   // 2 MB   W_O bf16
    float* zl  = (float*)(ws + 12582912); // 256 KB logits fp32 [B][H][S]
    u16*   zr  = (u16*)(ws + 12845056);   // 132 KB reversed softmax bf16 [B][H][ZP]
    u16*   vt2 = (u16*)(ws + 12980224);   // 8 MB   v^T bf16 [1024][B*S]
    u16*   cv  = (u16*)(ws + 21368832);   // 8 MB   conv out bf16 [4096][1024]

    cast_all<<<6144, 256, 0, stream>>>(x, W_V, W_O, xb, wvb, wob);
    logits_kernel<<<256, 256, 0, stream>>>(x, W_A, zl);
    // v^T[e][b*S+s] = sum_k W_V[e,k] * x[b,s,k]; blocks 256..287 do softmax
    gemm128<0, 0, true><<<288, 512, 0, stream>>>(wvb, xb, vt2, nullptr, nullptr,
                                                 1024, 4096, 1024, zl, zr);
    conv_kernel<<<512, 256, 0, stream>>>(zr, vt2, cv);
    gemm128<1, 1, false><<<256, 512, 0, stream>>>(cv, wob, nullptr, (float*)d_out, b_O,
                                                  4096, 1024, 1024, nullptr, nullptr);
}